// Round 25
// baseline (73.840 us; speedup 1.0000x reference)
//
#include <hip/hip_runtime.h>
#include <math.h>

#define NN 262144
#define PP 64
#define QQ 64
#define TT 2048
#define JJ 512
#define BB 8
#define HH 64

__device__ __forceinline__ float lane_bcast(float v, int l) {
  return __int_as_float(__builtin_amdgcn_readlane(__float_as_int(v), l));
}

// ------- kernel 1: ew = exp(K.Scols); blocks 0-8 also compute seg_start -----
__global__ __launch_bounds__(256) void k_wp(const float* __restrict__ Kmat,
                                            const int* __restrict__ idx,
                                            const float* __restrict__ S,
                                            const int* __restrict__ seg_ids,
                                            float* __restrict__ ew,
                                            int* __restrict__ seg_start) {
  int tid = threadIdx.x;
  int gtid = blockIdx.x * 256 + tid;
  if (gtid <= TT) {
    int lo = 0, hi = NN;
    while (lo < hi) {
      int mid = (lo + hi) >> 1;
      if (seg_ids[mid] < gtid) lo = mid + 1; else hi = mid;
    }
    seg_start[gtid] = lo;
  }
  __shared__ __align__(16) float s_lds[BB * PP];  // [b][p]
  for (int i = tid; i < BB * PP; i += 256) {
    int p = i >> 3, b = i & 7;
    s_lds[b * PP + p] = S[p * JJ + idx[b]];
  }
  __syncthreads();
  int n = blockIdx.x * 64 + (tid >> 2);
  int sub = tid & 3;
  const float4* Kp = reinterpret_cast<const float4*>(Kmat + (size_t)n * PP + sub * 16);
  float4 kq[4];
#pragma unroll
  for (int j = 0; j < 4; ++j) kq[j] = Kp[j];
  float acc[8];
#pragma unroll
  for (int b = 0; b < 8; ++b) acc[b] = 0.f;
#pragma unroll
  for (int j4 = 0; j4 < 4; ++j4) {
    float4 kk = kq[j4];
#pragma unroll
    for (int b = 0; b < 8; ++b) {
      const float4 sv = *reinterpret_cast<const float4*>(&s_lds[b * PP + sub * 16 + j4 * 4]);
      acc[b] += kk.x * sv.x + kk.y * sv.y + kk.z * sv.z + kk.w * sv.w;
    }
  }
#pragma unroll
  for (int b = 0; b < 8; ++b) {
    acc[b] += __shfl_xor(acc[b], 1);
    acc[b] += __shfl_xor(acc[b], 2);
  }
  float ox = (sub == 0) ? acc[0] : (sub == 1) ? acc[2] : (sub == 2) ? acc[4] : acc[6];
  float oy = (sub == 0) ? acc[1] : (sub == 1) ? acc[3] : (sub == 2) ? acc[5] : acc[7];
  reinterpret_cast<float2*>(ew + (size_t)n * 8)[sub] =
      make_float2(__expf(ox), __expf(oy));
}

// ------- kernel 2: segment sums (proven shuffle-free) + FUSED GI matvec -----
// Epilogue keeps M[t] tile in LDS; wave w then computes GI rows for b=w with
// k_gi's exact matvec (padded Wt LDS + lane_bcast). M never touches global.
__global__ __launch_bounds__(512) void k_segGI(const float* __restrict__ ew,
                                               const float* __restrict__ V,
                                               const int* __restrict__ seg_start,
                                               const float* __restrict__ W_ih,
                                               const float* __restrict__ b_ih,
                                               float* __restrict__ GI) {
  __shared__ __align__(16) float accred[8][8][64];   // 16 KB
  __shared__ float reds[8][8];
  __shared__ __align__(16) float Mtile[512];         // 2 KB
  __shared__ float Wt[64 * 193];                     // 49.4 KB
  int tid = threadIdx.x;
  int t = blockIdx.x;
  int lane = tid & 63;
  int w = __builtin_amdgcn_readfirstlane(tid >> 6);   // wave-uniform slice id

  // stage W_ih^T (padded) -- independent of the segment loop
  for (int i = tid; i < 192 * 64; i += 512) {
    int g = i >> 6, k = i & 63;
    Wt[k * 193 + g] = W_ih[i];
  }

  int s = seg_start[t], e = seg_start[t + 1];
  int len = e - s;
  int chunk = (len + 7) >> 3;
  int b0 = __builtin_amdgcn_readfirstlane(s + w * chunk);
  int b1 = b0 + chunk; if (b1 > e) b1 = e;
  b1 = __builtin_amdgcn_readfirstlane(b1);
  if (b1 < b0) b1 = b0;

  float acc[8], se[8];
#pragma unroll
  for (int b = 0; b < 8; ++b) { acc[b] = 0.f; se[b] = 0.f; }

  int r = b0;
  for (; r + 4 <= b1; r += 4) {
#pragma unroll
    for (int u = 0; u < 4; ++u) {
      const float* er = ew + (size_t)(r + u) * 8;   // wave-uniform -> s_load
      float e0 = er[0], e1 = er[1], e2 = er[2], e3 = er[3];
      float e4 = er[4], e5 = er[5], e6 = er[6], e7 = er[7];
      float v = V[(size_t)(r + u) * QQ + lane];
      acc[0] += e0 * v; acc[1] += e1 * v; acc[2] += e2 * v; acc[3] += e3 * v;
      acc[4] += e4 * v; acc[5] += e5 * v; acc[6] += e6 * v; acc[7] += e7 * v;
      se[0] += e0; se[1] += e1; se[2] += e2; se[3] += e3;
      se[4] += e4; se[5] += e5; se[6] += e6; se[7] += e7;
    }
  }
  for (; r < b1; ++r) {
    const float* er = ew + (size_t)r * 8;
    float e0 = er[0], e1 = er[1], e2 = er[2], e3 = er[3];
    float e4 = er[4], e5 = er[5], e6 = er[6], e7 = er[7];
    float v = V[(size_t)r * QQ + lane];
    acc[0] += e0 * v; acc[1] += e1 * v; acc[2] += e2 * v; acc[3] += e3 * v;
    acc[4] += e4 * v; acc[5] += e5 * v; acc[6] += e6 * v; acc[7] += e7 * v;
    se[0] += e0; se[1] += e1; se[2] += e2; se[3] += e3;
    se[4] += e4; se[5] += e5; se[6] += e6; se[7] += e7;
  }

#pragma unroll
  for (int b = 0; b < 8; ++b) accred[w][b][lane] = acc[b];
  if (lane == 0) {
#pragma unroll
    for (int b = 0; b < 8; ++b) reds[w][b] = se[b];
  }
  __syncthreads();
  {
    int o = tid;   // 512 threads cover 512 M-tile entries in one pass
    int b = o >> 6, q = o & 63;
    float dd = 0.f, sum = 0.f;
#pragma unroll
    for (int jj = 0; jj < 8; ++jj) { dd += reds[jj][b]; sum += accred[jj][b][q]; }
    float inv = (dd > 0.f) ? 1.f / dd : 0.f;
    Mtile[o] = sum * inv;                 // M[t][b][q], LDS only
  }
  __syncthreads();

  // ---- fused GI: wave w computes rho = w*TT + t (b = w) ----
  {
    float x = Mtile[w * 64 + lane];
    float a0 = b_ih[lane], a1 = b_ih[64 + lane], a2 = b_ih[128 + lane];
#pragma unroll
    for (int k = 0; k < 64; ++k) {
      float w0 = Wt[k * 193 + lane];
      float w1 = Wt[k * 193 + 64 + lane];
      float w2 = Wt[k * 193 + 128 + lane];
      float xk = lane_bcast(x, k);
      a0 += w0 * xk; a1 += w1 * xk; a2 += w2 * xk;
    }
    size_t rho = (size_t)w * TT + t;
    GI[rho * 192 + lane]       = a0;
    GI[rho * 192 + 64 + lane]  = a1;
    GI[rho * 192 + 128 + lane] = a2;
  }
}

// -------- kernel 3: GRU, one t-row per wave, b128 W reads, padded LDS -------
__global__ __launch_bounds__(256) void k_gru(const float* __restrict__ GI,
                                             const float* __restrict__ W_hh,
                                             const float* __restrict__ b_hh,
                                             const float* __restrict__ w_out,
                                             const float* __restrict__ b_out,
                                             float* __restrict__ preds) {
  __shared__ __align__(16) float Wl[192 * 68];
  int tid = threadIdx.x;
  for (int i = tid; i < 192 * 16; i += 256) {
    int g = i >> 4, c = i & 15;
    *reinterpret_cast<float4*>(&Wl[g * 68 + c * 4]) =
        *reinterpret_cast<const float4*>(W_hh + g * 64 + c * 4);
  }
  __syncthreads();
  int lane = tid & 63, wv = tid >> 6;
  int t = blockIdx.x * 4 + wv;
  float bh0 = b_hh[lane], bh1 = b_hh[64 + lane], bh2 = b_hh[128 + lane];
  float wo = w_out[lane];
  float bo = b_out[0];
  const float* w0base = &Wl[lane * 68];
  const float* w1base = &Wl[(64 + lane) * 68];
  const float* w2base = &Wl[(128 + lane) * 68];

  float gr[8], gz[8], gn[8];
#pragma unroll
  for (int b = 0; b < 8; ++b) {
    size_t base = ((size_t)b * TT + t) * 192;
    gr[b] = GI[base + lane];
    gz[b] = GI[base + 64 + lane];
    gn[b] = GI[base + 128 + lane];
  }

  float h;
  {
    float r = 1.f / (1.f + __expf(-(gr[0] + bh0)));
    float z = 1.f / (1.f + __expf(-(gz[0] + bh1)));
    float nv = tanhf(gn[0] + r * bh2);
    h = (1.f - z) * nv;
    float pv = h * wo;
#pragma unroll
    for (int off = 32; off; off >>= 1) pv += __shfl_xor(pv, off);
    if (lane == 0) preds[t] = pv + bo;
  }
#pragma unroll
  for (int b = 1; b < 8; ++b) {
    float ar = bh0, az = bh1, an = bh2;
#pragma unroll
    for (int c = 0; c < 16; ++c) {
      const float4 w0 = *reinterpret_cast<const float4*>(w0base + c * 4);
      const float4 w1 = *reinterpret_cast<const float4*>(w1base + c * 4);
      const float4 w2 = *reinterpret_cast<const float4*>(w2base + c * 4);
      float a0 = lane_bcast(h, c * 4 + 0), a1 = lane_bcast(h, c * 4 + 1);
      float a2 = lane_bcast(h, c * 4 + 2), a3 = lane_bcast(h, c * 4 + 3);
      ar += w0.x * a0 + w0.y * a1 + w0.z * a2 + w0.w * a3;
      az += w1.x * a0 + w1.y * a1 + w1.z * a2 + w1.w * a3;
      an += w2.x * a0 + w2.y * a1 + w2.z * a2 + w2.w * a3;
    }
    float r = 1.f / (1.f + __expf(-(gr[b] + ar)));
    float z = 1.f / (1.f + __expf(-(gz[b] + az)));
    float nv = tanhf(gn[b] + r * an);
    h = (1.f - z) * nv + z * h;
    float pv = h * wo;
#pragma unroll
    for (int off = 32; off; off >>= 1) pv += __shfl_xor(pv, off);
    if (lane == 0) preds[(size_t)b * TT + t] = pv + bo;
  }
}

extern "C" void kernel_launch(void* const* d_in, const int* in_sizes, int n_in,
                              void* d_out, int out_size, void* d_ws, size_t ws_size,
                              hipStream_t stream) {
  const int*   idx     = (const int*)d_in[0];
  const int*   seg_ids = (const int*)d_in[1];
  const float* Kmat    = (const float*)d_in[2];
  const float* V       = (const float*)d_in[3];
  const float* S       = (const float*)d_in[4];
  const float* W_ih    = (const float*)d_in[5];
  const float* W_hh    = (const float*)d_in[6];
  const float* b_ih    = (const float*)d_in[7];
  const float* b_hh    = (const float*)d_in[8];
  const float* w_out   = (const float*)d_in[9];
  const float* b_out   = (const float*)d_in[10];
  float* out = (float*)d_out;

  char* ws = (char*)d_ws;
  int*   seg_start = (int*)(ws + 0);       // (T+1) ints         8448 B
  float* ew = (float*)(ws + 8448);         // N*8 f              8.4 MB
  float* GI = (float*)(ws + 8397056);      // 8*T*192 f         12.6 MB

  hipLaunchKernelGGL(k_wp, dim3(NN / 64), dim3(256), 0, stream,
                     Kmat, idx, S, seg_ids, ew, seg_start);
  hipLaunchKernelGGL(k_segGI, dim3(TT), dim3(512), 0, stream,
                     ew, V, seg_start, W_ih, b_ih, GI);
  hipLaunchKernelGGL(k_gru, dim3(512), dim3(256), 0, stream,
                     GI, W_hh, b_hh, w_out, b_out, out);
}

// Round 26
// 69.638 us; speedup vs baseline: 1.0603x; 1.0603x over previous
//
#include <hip/hip_runtime.h>
#include <math.h>

#define NN 262144
#define PP 64
#define QQ 64
#define TT 2048
#define JJ 512
#define BB 8
#define HH 64

__device__ __forceinline__ float lane_bcast(float v, int l) {
  return __int_as_float(__builtin_amdgcn_readlane(__float_as_int(v), l));
}

// ------- kernel 1: ew = exp(K.Scols); blocks 0-8 also compute seg_start -----
__global__ __launch_bounds__(256) void k_wp(const float* __restrict__ Kmat,
                                            const int* __restrict__ idx,
                                            const float* __restrict__ S,
                                            const int* __restrict__ seg_ids,
                                            float* __restrict__ ew,
                                            int* __restrict__ seg_start) {
  int tid = threadIdx.x;
  int gtid = blockIdx.x * 256 + tid;
  if (gtid <= TT) {
    int lo = 0, hi = NN;
    while (lo < hi) {
      int mid = (lo + hi) >> 1;
      if (seg_ids[mid] < gtid) lo = mid + 1; else hi = mid;
    }
    seg_start[gtid] = lo;
  }
  __shared__ __align__(16) float s_lds[BB * PP];  // [b][p]
  for (int i = tid; i < BB * PP; i += 256) {
    int p = i >> 3, b = i & 7;
    s_lds[b * PP + p] = S[p * JJ + idx[b]];
  }
  __syncthreads();
  int n = blockIdx.x * 64 + (tid >> 2);
  int sub = tid & 3;
  const float4* Kp = reinterpret_cast<const float4*>(Kmat + (size_t)n * PP + sub * 16);
  float4 kq[4];
#pragma unroll
  for (int j = 0; j < 4; ++j) kq[j] = Kp[j];
  float acc[8];
#pragma unroll
  for (int b = 0; b < 8; ++b) acc[b] = 0.f;
#pragma unroll
  for (int j4 = 0; j4 < 4; ++j4) {
    float4 kk = kq[j4];
#pragma unroll
    for (int b = 0; b < 8; ++b) {
      const float4 sv = *reinterpret_cast<const float4*>(&s_lds[b * PP + sub * 16 + j4 * 4]);
      acc[b] += kk.x * sv.x + kk.y * sv.y + kk.z * sv.z + kk.w * sv.w;
    }
  }
#pragma unroll
  for (int b = 0; b < 8; ++b) {
    acc[b] += __shfl_xor(acc[b], 1);
    acc[b] += __shfl_xor(acc[b], 2);
  }
  float ox = (sub == 0) ? acc[0] : (sub == 1) ? acc[2] : (sub == 2) ? acc[4] : acc[6];
  float oy = (sub == 0) ? acc[1] : (sub == 1) ? acc[3] : (sub == 2) ? acc[5] : acc[7];
  reinterpret_cast<float2*>(ew + (size_t)n * 8)[sub] =
      make_float2(__expf(ox), __expf(oy));
}

// ------- kernel 2: shuffle-free segment sums, 8 slice-waves (512 thr) -------
__global__ __launch_bounds__(512) void k_segS(const float* __restrict__ ew,
                                              const float* __restrict__ V,
                                              const int* __restrict__ seg_start,
                                              float* __restrict__ M) {
  __shared__ __align__(16) float accred[8][8][64];   // 16 KB
  __shared__ float reds[8][8];
  int tid = threadIdx.x;
  int t = blockIdx.x;
  int lane = tid & 63;
  int w = __builtin_amdgcn_readfirstlane(tid >> 6);   // wave-uniform slice id
  int s = seg_start[t], e = seg_start[t + 1];
  int len = e - s;
  int chunk = (len + 7) >> 3;
  int b0 = __builtin_amdgcn_readfirstlane(s + w * chunk);
  int b1 = b0 + chunk; if (b1 > e) b1 = e;
  b1 = __builtin_amdgcn_readfirstlane(b1);
  if (b1 < b0) b1 = b0;

  float acc[8], se[8];
#pragma unroll
  for (int b = 0; b < 8; ++b) { acc[b] = 0.f; se[b] = 0.f; }

  int r = b0;
  for (; r + 4 <= b1; r += 4) {
#pragma unroll
    for (int u = 0; u < 4; ++u) {
      const float* er = ew + (size_t)(r + u) * 8;   // wave-uniform -> s_load
      float e0 = er[0], e1 = er[1], e2 = er[2], e3 = er[3];
      float e4 = er[4], e5 = er[5], e6 = er[6], e7 = er[7];
      float v = V[(size_t)(r + u) * QQ + lane];
      acc[0] += e0 * v; acc[1] += e1 * v; acc[2] += e2 * v; acc[3] += e3 * v;
      acc[4] += e4 * v; acc[5] += e5 * v; acc[6] += e6 * v; acc[7] += e7 * v;
      se[0] += e0; se[1] += e1; se[2] += e2; se[3] += e3;
      se[4] += e4; se[5] += e5; se[6] += e6; se[7] += e7;
    }
  }
  for (; r < b1; ++r) {
    const float* er = ew + (size_t)r * 8;
    float e0 = er[0], e1 = er[1], e2 = er[2], e3 = er[3];
    float e4 = er[4], e5 = er[5], e6 = er[6], e7 = er[7];
    float v = V[(size_t)r * QQ + lane];
    acc[0] += e0 * v; acc[1] += e1 * v; acc[2] += e2 * v; acc[3] += e3 * v;
    acc[4] += e4 * v; acc[5] += e5 * v; acc[6] += e6 * v; acc[7] += e7 * v;
    se[0] += e0; se[1] += e1; se[2] += e2; se[3] += e3;
    se[4] += e4; se[5] += e5; se[6] += e6; se[7] += e7;
  }

#pragma unroll
  for (int b = 0; b < 8; ++b) accred[w][b][lane] = acc[b];
  if (lane == 0) {
#pragma unroll
    for (int b = 0; b < 8; ++b) reds[w][b] = se[b];
  }
  __syncthreads();
  {
    int o = tid;   // 512 threads cover all 512 outputs in one pass
    int b = o >> 6, q = o & 63;
    float dd = 0.f, sum = 0.f;
#pragma unroll
    for (int jj = 0; jj < 8; ++jj) { dd += reds[jj][b]; sum += accred[jj][b][q]; }
    float inv = (dd > 0.f) ? 1.f / dd : 0.f;
    M[(size_t)t * 512 + o] = sum * inv;   // M[t][b][q]
  }
}

// -------- kernel 3: GI[rho][g] = W_ih[g,:] . X[rho,:] + b_ih ----------------
__global__ __launch_bounds__(256) void k_gi(const float* __restrict__ M,
                                            const float* __restrict__ W_ih,
                                            const float* __restrict__ b_ih,
                                            float* __restrict__ GI) {
  __shared__ float Wt[64 * 193];
  int tid = threadIdx.x;
  for (int i = tid; i < 192 * 64; i += 256) {
    int g = i >> 6, k = i & 63;
    Wt[k * 193 + g] = W_ih[i];
  }
  __syncthreads();
  int lane = tid & 63, wv = tid >> 6;
  int row0 = blockIdx.x * 32 + wv * 8;
  float x[8];
#pragma unroll
  for (int rr = 0; rr < 8; ++rr) {
    int rho = row0 + rr;
    int b = rho >> 11, t = rho & 2047;
    x[rr] = M[((size_t)t * 8 + b) * 64 + lane];
  }
  float bi0 = b_ih[lane], bi1 = b_ih[64 + lane], bi2 = b_ih[128 + lane];
  float a0[8], a1[8], a2[8];
#pragma unroll
  for (int rr = 0; rr < 8; ++rr) { a0[rr] = bi0; a1[rr] = bi1; a2[rr] = bi2; }
#pragma unroll
  for (int k = 0; k < 64; ++k) {
    float w0 = Wt[k * 193 + lane];
    float w1 = Wt[k * 193 + 64 + lane];
    float w2 = Wt[k * 193 + 128 + lane];
#pragma unroll
    for (int rr = 0; rr < 8; ++rr) {
      float xk = lane_bcast(x[rr], k);
      a0[rr] += w0 * xk; a1[rr] += w1 * xk; a2[rr] += w2 * xk;
    }
  }
#pragma unroll
  for (int rr = 0; rr < 8; ++rr) {
    size_t rho = (size_t)row0 + rr;
    GI[rho * 192 + lane]       = a0[rr];
    GI[rho * 192 + 64 + lane]  = a1[rr];
    GI[rho * 192 + 128 + lane] = a2[rr];
  }
}

// -------- kernel 4: GRU, one t-row per wave, b128 W reads, padded LDS -------
__global__ __launch_bounds__(256) void k_gru(const float* __restrict__ GI,
                                             const float* __restrict__ W_hh,
                                             const float* __restrict__ b_hh,
                                             const float* __restrict__ w_out,
                                             const float* __restrict__ b_out,
                                             float* __restrict__ preds) {
  __shared__ __align__(16) float Wl[192 * 68];
  int tid = threadIdx.x;
  for (int i = tid; i < 192 * 16; i += 256) {
    int g = i >> 4, c = i & 15;
    *reinterpret_cast<float4*>(&Wl[g * 68 + c * 4]) =
        *reinterpret_cast<const float4*>(W_hh + g * 64 + c * 4);
  }
  __syncthreads();
  int lane = tid & 63, wv = tid >> 6;
  int t = blockIdx.x * 4 + wv;
  float bh0 = b_hh[lane], bh1 = b_hh[64 + lane], bh2 = b_hh[128 + lane];
  float wo = w_out[lane];
  float bo = b_out[0];
  const float* w0base = &Wl[lane * 68];
  const float* w1base = &Wl[(64 + lane) * 68];
  const float* w2base = &Wl[(128 + lane) * 68];

  float gr[8], gz[8], gn[8];
#pragma unroll
  for (int b = 0; b < 8; ++b) {
    size_t base = ((size_t)b * TT + t) * 192;
    gr[b] = GI[base + lane];
    gz[b] = GI[base + 64 + lane];
    gn[b] = GI[base + 128 + lane];
  }

  float h;
  {
    float r = 1.f / (1.f + __expf(-(gr[0] + bh0)));
    float z = 1.f / (1.f + __expf(-(gz[0] + bh1)));
    float nv = tanhf(gn[0] + r * bh2);
    h = (1.f - z) * nv;
    float pv = h * wo;
#pragma unroll
    for (int off = 32; off; off >>= 1) pv += __shfl_xor(pv, off);
    if (lane == 0) preds[t] = pv + bo;
  }
#pragma unroll
  for (int b = 1; b < 8; ++b) {
    float ar = bh0, az = bh1, an = bh2;
#pragma unroll
    for (int c = 0; c < 16; ++c) {
      const float4 w0 = *reinterpret_cast<const float4*>(w0base + c * 4);
      const float4 w1 = *reinterpret_cast<const float4*>(w1base + c * 4);
      const float4 w2 = *reinterpret_cast<const float4*>(w2base + c * 4);
      float a0 = lane_bcast(h, c * 4 + 0), a1 = lane_bcast(h, c * 4 + 1);
      float a2 = lane_bcast(h, c * 4 + 2), a3 = lane_bcast(h, c * 4 + 3);
      ar += w0.x * a0 + w0.y * a1 + w0.z * a2 + w0.w * a3;
      az += w1.x * a0 + w1.y * a1 + w1.z * a2 + w1.w * a3;
      an += w2.x * a0 + w2.y * a1 + w2.z * a2 + w2.w * a3;
    }
    float r = 1.f / (1.f + __expf(-(gr[b] + ar)));
    float z = 1.f / (1.f + __expf(-(gz[b] + az)));
    float nv = tanhf(gn[b] + r * an);
    h = (1.f - z) * nv + z * h;
    float pv = h * wo;
#pragma unroll
    for (int off = 32; off; off >>= 1) pv += __shfl_xor(pv, off);
    if (lane == 0) preds[(size_t)b * TT + t] = pv + bo;
  }
}

extern "C" void kernel_launch(void* const* d_in, const int* in_sizes, int n_in,
                              void* d_out, int out_size, void* d_ws, size_t ws_size,
                              hipStream_t stream) {
  const int*   idx     = (const int*)d_in[0];
  const int*   seg_ids = (const int*)d_in[1];
  const float* Kmat    = (const float*)d_in[2];
  const float* V       = (const float*)d_in[3];
  const float* S       = (const float*)d_in[4];
  const float* W_ih    = (const float*)d_in[5];
  const float* W_hh    = (const float*)d_in[6];
  const float* b_ih    = (const float*)d_in[7];
  const float* b_hh    = (const float*)d_in[8];
  const float* w_out   = (const float*)d_in[9];
  const float* b_out   = (const float*)d_in[10];
  float* out = (float*)d_out;

  char* ws = (char*)d_ws;
  int*   seg_start = (int*)(ws + 0);       // (T+1) ints         8448 B
  float* ew = (float*)(ws + 8448);         // N*8 f              8.4 MB
  float* M  = (float*)(ws + 8397056);      // T*8*64 f           4.2 MB
  float* GI = (float*)(ws + 12591360);     // 8*T*192 f         12.6 MB

  hipLaunchKernelGGL(k_wp, dim3(NN / 64), dim3(256), 0, stream,
                     Kmat, idx, S, seg_ids, ew, seg_start);
  hipLaunchKernelGGL(k_segS, dim3(TT), dim3(512), 0, stream, ew, V, seg_start, M);
  hipLaunchKernelGGL(k_gi, dim3(512), dim3(256), 0, stream, M, W_ih, b_ih, GI);
  hipLaunchKernelGGL(k_gru, dim3(512), dim3(256), 0, stream, GI, W_hh, b_hh, w_out, b_out, out);
}